// Round 1
// baseline (290.936 us; speedup 1.0000x reference)
//
#include <hip/hip_runtime.h>
#include <stdint.h>

#define MAX_ITERS 20
#define EPSV 1e-7f
#define CLIPV 1e-7f

typedef __attribute__((ext_vector_type(8))) short short8;
typedef __attribute__((ext_vector_type(4))) float f4;

__device__ __forceinline__ f4 mfma_bf16(short8 a, short8 b, f4 c) {
    return __builtin_amdgcn_mfma_f32_16x16x32_bf16(a, b, c, 0, 0, 0);
}

// butterfly sum over the 64-lane wave; every lane gets the total
__device__ __forceinline__ float wsum64(float v) {
#pragma unroll
    for (int m = 32; m >= 1; m >>= 1) v += __shfl_xor(v, m, 64);
    return v;
}

// split 8 fp32 -> truncated-bf16 hi + bf16(lo) residual
__device__ __forceinline__ void cvt_hilo(const float* v, short8& hi, short8& lo) {
#pragma unroll
    for (int i = 0; i < 8; ++i) {
        float x = v[i];
        uint32_t u = __float_as_uint(x);
        float hf = __uint_as_float(u & 0xFFFF0000u);
        float lf = x - hf;
        hi[i] = (short)(u >> 16);
        lo[i] = (short)(__float_as_uint(lf) >> 16);
    }
}

__global__ void __launch_bounds__(256) karcher(const float* __restrict__ X,
                                               float* __restrict__ out,
                                               int n_groups) {
    // per-wave Gram (32x32, stride-33 pad -> conflict-free row reads) + inv norms
    __shared__ float sG[4][32 * 33];
    __shared__ float sInv[4][32];

    const int lane = threadIdx.x & 63;
    const int wid  = threadIdx.x >> 6;
    const int g    = blockIdx.x * 4 + wid;
    if (g >= n_groups) return;  // n_groups % 4 == 0: never diverges within a block

    const float* Xg = X + (size_t)g * (32 * 128);
    const int col  = lane & 15;   // A-row / B-col within a 16-tile
    const int quad = lane >> 4;   // k-subchunk selector

    // ---------------- Phase 1: Gram = Xraw * Xraw^T via MFMA (hi/lo split) ----
    f4 acc00 = {0.f, 0.f, 0.f, 0.f};
    f4 acc01 = acc00, acc10 = acc00, acc11 = acc00;

#pragma unroll
    for (int kc = 0; kc < 4; ++kc) {
        // lane loads exactly its own fragment data: row (col / col+16), dims kc*32+quad*8 .. +7
        const float* p0 = Xg + col * 128 + kc * 32 + quad * 8;
        const float* p1 = p0 + 16 * 128;
        float r0[8], r1[8];
        *(float4*)(r0)     = *(const float4*)(p0);
        *(float4*)(r0 + 4) = *(const float4*)(p0 + 4);
        *(float4*)(r1)     = *(const float4*)(p1);
        *(float4*)(r1 + 4) = *(const float4*)(p1 + 4);
        short8 H0, L0, H1, L1;
        cvt_hilo(r0, H0, L0);
        cvt_hilo(r1, H1, L1);
        // G ~= Hi*Hi^T + Hi*Lo^T + Lo*Hi^T  (Lo*Lo^T ~ 1e-5, dropped)
        acc00 = mfma_bf16(H0, H0, acc00);
        acc00 = mfma_bf16(H0, L0, acc00);
        acc00 = mfma_bf16(L0, H0, acc00);
        acc01 = mfma_bf16(H0, H1, acc01);
        acc01 = mfma_bf16(H0, L1, acc01);
        acc01 = mfma_bf16(L0, H1, acc01);
        acc10 = mfma_bf16(H1, H0, acc10);
        acc10 = mfma_bf16(H1, L0, acc10);
        acc10 = mfma_bf16(L1, H0, acc10);
        acc11 = mfma_bf16(H1, H1, acc11);
        acc11 = mfma_bf16(H1, L1, acc11);
        acc11 = mfma_bf16(L1, H1, acc11);
    }

    // C/D layout: col = lane&15, row = quad*4 + reg  (G symmetric -> transpose-safe)
    float* Gw = sG[wid];
#pragma unroll
    for (int i = 0; i < 4; ++i) {
        int rw = quad * 4 + i;
        Gw[rw * 33 + col]             = acc00[i];
        Gw[rw * 33 + col + 16]        = acc01[i];
        Gw[(rw + 16) * 33 + col]      = acc10[i];
        Gw[(rw + 16) * 33 + col + 16] = acc11[i];
    }
    __syncthreads();

    // ---------------- Phase 2: normalize rows (point norms from diag) ---------
    const int r = lane & 31;  // this lane's row; duplicated across half-waves
    {
        float d = Gw[r * 33 + r];
        sInv[wid][r] = 1.0f / fmaxf(sqrtf(d), 1e-12f);  // matches max(||x||,1e-12)
    }
    __syncthreads();

    float Grow[32];
    {
        float invr = sInv[wid][r];
#pragma unroll
        for (int j = 0; j < 32; ++j)
            Grow[j] = Gw[r * 33 + j] * (invr * sInv[wid][j]);
    }

    // ---------------- Phase 3: init mu = normalize(mean(Xn)) in coeff space ---
    float a  = 1.0f / 32.0f;  // alpha_r
    float ga = 0.0f;          // (G*alpha)_r  == dot_r
#pragma unroll
    for (int j = 0; j < 32; ++j) ga += Grow[j];
    ga *= (1.0f / 32.0f);
    {
        float n2   = wsum64(a * ga) * 0.5f;  // halves duplicated -> *0.5
        float inv0 = 1.0f / fmaxf(sqrtf(n2), 1e-12f);
        a *= inv0;
        ga *= inv0;
    }

    // ---------------- Phase 4: 20 Karcher iterations in 32-dim Gram space -----
    for (int it = 0; it < MAX_ITERS; ++it) {
        float x  = fminf(fmaxf(ga, -1.0f + CLIPV), 1.0f - CLIPV);
        float th = acosf(x);
        float st = fmaxf(sqrtf(fmaxf(1.0f - x * x, 0.0f)), EPSV);  // sin(acos(x))
        float w  = __fdividef(th, st);
        float C  = wsum64(w * ga) * 0.5f;          // sum_n w_n * dot_n
        float beta = (w - C * a) * (1.0f / 32.0f); // v = sum beta_n Xn_n
        float gb = 0.0f;                           // (G*beta)_r
#pragma unroll
        for (int j = 0; j < 32; ++j) {
            float bj = __int_as_float(
                __builtin_amdgcn_readlane(__float_as_int(beta), j));
            gb += Grow[j] * bj;
        }
        float vv = wsum64(beta * gb) * 0.5f;       // ||v||^2 = beta^T G beta
        float vs = fmaxf(sqrtf(fmaxf(vv, 0.0f)), EPSV);
        float cv = __cosf(vs);
        float sv = __fdividef(__sinf(vs), vs);
        // exp map; v perp mu exactly -> ||mu_new|| = 1, re-normalize skipped
        a  = cv * a  + sv * beta;
        ga = cv * ga + sv * gb;
    }

    // ---------------- Phase 5: loss = mean_g sum_n acos(clip(dot))^2 ----------
    float xf = fminf(fmaxf(ga, -1.0f + CLIPV), 1.0f - CLIPV);
    float t  = acosf(xf);
    float ls = wsum64(t * t) * 0.5f;
    if (lane == 0) atomicAdd(out, ls / (float)n_groups);
}

extern "C" void kernel_launch(void* const* d_in, const int* in_sizes, int n_in,
                              void* d_out, int out_size, void* d_ws, size_t ws_size,
                              hipStream_t stream) {
    const float* X = (const float*)d_in[0];
    float* out = (float*)d_out;
    int n_groups = in_sizes[0] / (32 * 128);   // 8000
    hipMemsetAsync(d_out, 0, sizeof(float), stream);  // d_out is poisoned 0xAA
    int blocks = (n_groups + 3) / 4;            // 4 waves/block, 1 group/wave
    karcher<<<blocks, 256, 0, stream>>>(X, out, n_groups);
}

// Round 2
// 278.129 us; speedup vs baseline: 1.0460x; 1.0460x over previous
//
#include <hip/hip_runtime.h>
#include <stdint.h>

#define MAX_ITERS 20
#define EPSV 1e-7f
#define CLIPV 1e-7f
#define PI_F 3.14159265358979f
#define PIO2_F 1.57079632679490f

typedef __attribute__((ext_vector_type(8))) short short8;
typedef __attribute__((ext_vector_type(4))) float f4;

__device__ __forceinline__ f4 mfma_bf16(short8 a, short8 b, f4 c) {
    return __builtin_amdgcn_mfma_f32_16x16x32_bf16(a, b, c, 0, 0, 0);
}

__device__ __forceinline__ float rl(float v, int l) {
    return __int_as_float(__builtin_amdgcn_readlane(__float_as_int(v), l));
}

// DPP-routed add: v += v[lane ^ k], VALU pipe (no LDS/bpermute latency)
template <int CTRL>
__device__ __forceinline__ float dpp_add(float v) {
    int p = __builtin_amdgcn_update_dpp(0, __float_as_int(v), CTRL, 0xF, 0xF, true);
    return v + __int_as_float(p);
}

// Sum over the 32 distinct rows (halves of the wave hold duplicates).
// xor1/2/4/8 are row-local DPP patterns; 16<->combine via 2 readlanes.
// Result is wave-uniform.
__device__ __forceinline__ float rowsum32(float v) {
    v = dpp_add<0xB1>(v);   // quad_perm(1,0,3,2)  == xor1
    v = dpp_add<0x4E>(v);   // quad_perm(2,3,0,1)  == xor2
    v = dpp_add<0x141>(v);  // row_half_mirror     == xor4 (quad-uniform input)
    v = dpp_add<0x140>(v);  // row_mirror          == xor8 (8-uniform input)
    return rl(v, 0) + rl(v, 16);  // rows 0-15 + rows 16-31
}

// Branchless acos, |err| ~1e-7; input pre-clipped to (-1, 1).
__device__ __forceinline__ float fast_acos(float x) {
    float a = fabsf(x);
    bool big = a > 0.5f;
    float z = big ? 0.5f * (1.0f - a) : x * x;
    float s = big ? sqrtf(z) : x;   // asin argument (keeps sign in small branch)
    float p = fmaf(z, fmaf(z, fmaf(z, fmaf(z, 4.2163199048e-2f, 2.4181311049e-2f),
                                   4.5470025998e-2f), 7.4953002686e-2f),
                   1.6666752422e-1f);
    float r = fmaf(s * z, p, s);    // asin(s), |s| <= 0.5
    float big_val = (x < 0.0f) ? (PI_F - 2.0f * r) : (2.0f * r);
    return big ? big_val : (PIO2_F - r);
}

// split 8 fp32 -> truncated-bf16 hi + bf16(lo) residual
__device__ __forceinline__ void cvt_hilo(const float* v, short8& hi, short8& lo) {
#pragma unroll
    for (int i = 0; i < 8; ++i) {
        float x = v[i];
        uint32_t u = __float_as_uint(x);
        float hf = __uint_as_float(u & 0xFFFF0000u);
        float lf = x - hf;
        hi[i] = (short)(u >> 16);
        lo[i] = (short)(__float_as_uint(lf) >> 16);
    }
}

__global__ void __launch_bounds__(256) karcher(const float* __restrict__ X,
                                               float* __restrict__ out,
                                               int n_groups) {
    __shared__ float sG[4][32 * 33];   // stride-33: conflict-free row reads
    __shared__ float sInv[4][32];

    const int lane = threadIdx.x & 63;
    const int wid  = threadIdx.x >> 6;
    const int g    = blockIdx.x * 4 + wid;
    if (g >= n_groups) return;  // 8000 % 4 == 0: never diverges

    const float* Xg = X + (size_t)g * (32 * 128);
    const int col  = lane & 15;
    const int quad = lane >> 4;

    // ---- Phase 1: Gram = X X^T via MFMA, hi/lo bf16 split (err ~1e-5) ------
    f4 acc00 = {0.f, 0.f, 0.f, 0.f};
    f4 acc01 = acc00, acc10 = acc00, acc11 = acc00;
#pragma unroll
    for (int kc = 0; kc < 4; ++kc) {
        const float* p0 = Xg + col * 128 + kc * 32 + quad * 8;
        const float* p1 = p0 + 16 * 128;
        float r0[8], r1[8];
        *(float4*)(r0)     = *(const float4*)(p0);
        *(float4*)(r0 + 4) = *(const float4*)(p0 + 4);
        *(float4*)(r1)     = *(const float4*)(p1);
        *(float4*)(r1 + 4) = *(const float4*)(p1 + 4);
        short8 H0, L0, H1, L1;
        cvt_hilo(r0, H0, L0);
        cvt_hilo(r1, H1, L1);
        acc00 = mfma_bf16(H0, H0, acc00);
        acc00 = mfma_bf16(H0, L0, acc00);
        acc00 = mfma_bf16(L0, H0, acc00);
        acc01 = mfma_bf16(H0, H1, acc01);
        acc01 = mfma_bf16(H0, L1, acc01);
        acc01 = mfma_bf16(L0, H1, acc01);
        acc10 = mfma_bf16(H1, H0, acc10);
        acc10 = mfma_bf16(H1, L0, acc10);
        acc10 = mfma_bf16(L1, H0, acc10);
        acc11 = mfma_bf16(H1, H1, acc11);
        acc11 = mfma_bf16(H1, L1, acc11);
        acc11 = mfma_bf16(L1, H1, acc11);
    }

    float* Gw = sG[wid];
#pragma unroll
    for (int i = 0; i < 4; ++i) {   // C/D: col=lane&15, row=quad*4+i (G sym)
        int rw = quad * 4 + i;
        Gw[rw * 33 + col]             = acc00[i];
        Gw[rw * 33 + col + 16]        = acc01[i];
        Gw[(rw + 16) * 33 + col]      = acc10[i];
        Gw[(rw + 16) * 33 + col + 16] = acc11[i];
    }
    __syncthreads();

    // ---- Phase 2: normalized Gram row into VGPRs -----------------------------
    const int r = lane & 31;
    {
        float d = Gw[r * 33 + r];
        sInv[wid][r] = 1.0f / fmaxf(sqrtf(d), 1e-12f);
    }
    __syncthreads();

    float Grow[32];
    {
        float invr = sInv[wid][r];
#pragma unroll
        for (int j = 0; j < 32; ++j)
            Grow[j] = Gw[r * 33 + j] * (invr * sInv[wid][j]);
    }

    // ---- Phase 3: mu0 = normalize(mean(Xn)) in coefficient space ------------
    float a = 1.0f / 32.0f;
    float ga;
    {
        float s0 = 0, s1 = 0, s2 = 0, s3 = 0;
#pragma unroll
        for (int j = 0; j < 8; ++j) {
            s0 += Grow[j];
            s1 += Grow[j + 8];
            s2 += Grow[j + 16];
            s3 += Grow[j + 24];
        }
        ga = ((s0 + s1) + (s2 + s3)) * (1.0f / 32.0f);
        float n2   = rowsum32(a * ga);
        float inv0 = 1.0f / fmaxf(sqrtf(n2), 1e-12f);
        a  *= inv0;
        ga *= inv0;
    }

    // ---- Phase 4: Karcher iterations in 32-dim Gram space -------------------
    for (int it = 0; it < MAX_ITERS; ++it) {
        float x  = fminf(fmaxf(ga, -1.0f + CLIPV), 1.0f - CLIPV);
        float th = fast_acos(x);
        float st = fmaxf(sqrtf(fmaxf(1.0f - x * x, 0.0f)), EPSV);
        float w  = __fdividef(th, st);
        float C  = rowsum32(w * ga);               // sum_n w_n dot_n
        float beta = (w - C * a) * (1.0f / 32.0f); // v = sum beta_n Xn_n
        float gb0 = 0, gb1 = 0, gb2 = 0, gb3 = 0;  // (G beta)_r, 4 indep chains
#pragma unroll
        for (int j = 0; j < 8; ++j) {
            gb0 = fmaf(Grow[j],      rl(beta, j),      gb0);
            gb1 = fmaf(Grow[j + 8],  rl(beta, j + 8),  gb1);
            gb2 = fmaf(Grow[j + 16], rl(beta, j + 16), gb2);
            gb3 = fmaf(Grow[j + 24], rl(beta, j + 24), gb3);
        }
        float gb = (gb0 + gb1) + (gb2 + gb3);
        float vv = rowsum32(beta * gb);            // ||v||^2 = beta^T G beta
        float vs = fmaxf(sqrtf(fmaxf(vv, 0.0f)), EPSV);
        float cv = __cosf(vs);
        float sv = __fdividef(__sinf(vs), vs);
        a  = fmaf(sv, beta, cv * a);               // exp map (v perp mu)
        ga = fmaf(sv, gb, cv * ga);
        if (vs < 1e-6f) break;  // wave-uniform; residual drift < 2e-5 in mu
    }

    // ---- Phase 5: loss ------------------------------------------------------
    float xf = fminf(fmaxf(ga, -1.0f + CLIPV), 1.0f - CLIPV);
    float t  = fast_acos(xf);
    float ls = rowsum32(t * t);
    if (lane == 0) atomicAdd(out, ls / (float)n_groups);
}

extern "C" void kernel_launch(void* const* d_in, const int* in_sizes, int n_in,
                              void* d_out, int out_size, void* d_ws, size_t ws_size,
                              hipStream_t stream) {
    const float* X = (const float*)d_in[0];
    float* out = (float*)d_out;
    int n_groups = in_sizes[0] / (32 * 128);   // 8000
    hipMemsetAsync(d_out, 0, sizeof(float), stream);  // d_out is poisoned 0xAA
    int blocks = (n_groups + 3) / 4;
    karcher<<<blocks, 256, 0, stream>>>(X, out, n_groups);
}

// Round 4
// 212.470 us; speedup vs baseline: 1.3693x; 1.3090x over previous
//
#include <hip/hip_runtime.h>
#include <stdint.h>

#define MAX_ITERS 20
#define EPSV 1e-7f
#define CLIPV 1e-7f
#define PI_F 3.14159265358979f
#define PIO2_F 1.57079632679490f

typedef __attribute__((ext_vector_type(8))) short short8;
typedef __attribute__((ext_vector_type(4))) float f4;

__device__ __forceinline__ f4 mfma_bf16(short8 a, short8 b, f4 c) {
    return __builtin_amdgcn_mfma_f32_16x16x32_bf16(a, b, c, 0, 0, 0);
}

__device__ __forceinline__ float rl(float v, int l) {
    return __int_as_float(__builtin_amdgcn_readlane(__float_as_int(v), l));
}

// DPP-routed add: v += v[lane ^ k], VALU pipe (no LDS/bpermute latency)
template <int CTRL>
__device__ __forceinline__ float dpp_add(float v) {
    int p = __builtin_amdgcn_update_dpp(0, __float_as_int(v), CTRL, 0xF, 0xF, true);
    return v + __int_as_float(p);
}

// Sum over the 32 distinct rows (halves of the wave hold duplicates).
// Result is wave-uniform.
__device__ __forceinline__ float rowsum32(float v) {
    v = dpp_add<0xB1>(v);   // quad_perm(1,0,3,2)  == xor1
    v = dpp_add<0x4E>(v);   // quad_perm(2,3,0,1)  == xor2
    v = dpp_add<0x141>(v);  // row_half_mirror     == xor4
    v = dpp_add<0x140>(v);  // row_mirror          == xor8
    return rl(v, 0) + rl(v, 16);  // rows 0-15 + rows 16-31
}

// Branchless acos, |err| ~1e-7; input pre-clipped to (-1, 1).
__device__ __forceinline__ float fast_acos(float x) {
    float a = fabsf(x);
    bool big = a > 0.5f;
    float z = big ? 0.5f * (1.0f - a) : x * x;
    float s = big ? sqrtf(z) : x;
    float p = fmaf(z, fmaf(z, fmaf(z, fmaf(z, 4.2163199048e-2f, 2.4181311049e-2f),
                                   4.5470025998e-2f), 7.4953002686e-2f),
                   1.6666752422e-1f);
    float r = fmaf(s * z, p, s);    // asin(s), |s| <= 0.5
    float big_val = (x < 0.0f) ? (PI_F - 2.0f * r) : (2.0f * r);
    return big ? big_val : (PIO2_F - r);
}

// split 8 fp32 -> truncated-bf16 hi + bf16(lo) residual
__device__ __forceinline__ void cvt_hilo(const float* v, short8& hi, short8& lo) {
#pragma unroll
    for (int i = 0; i < 8; ++i) {
        float x = v[i];
        uint32_t u = __float_as_uint(x);
        float hf = __uint_as_float(u & 0xFFFF0000u);
        float lf = x - hf;
        hi[i] = (short)(u >> 16);
        lo[i] = (short)(__float_as_uint(lf) >> 16);
    }
}

__global__ void __launch_bounds__(256) karcher(const float* __restrict__ X,
                                               float* __restrict__ ws,
                                               int n_groups) {
    __shared__ float sG[4][32 * 33];   // stride-33: conflict-free row reads
    __shared__ float sInv[4][32];
    __shared__ float sPart[4];

    const int lane = threadIdx.x & 63;
    const int wid  = threadIdx.x >> 6;
    const int g    = blockIdx.x * 4 + wid;
    if (g >= n_groups) return;  // 8000 % 4 == 0: never diverges

    const float* Xg = X + (size_t)g * (32 * 128);
    const int col  = lane & 15;
    const int quad = lane >> 4;

    // ---- Phase 1: Gram = X X^T via MFMA, hi/lo bf16 split (err ~1e-5) ------
    f4 acc00 = {0.f, 0.f, 0.f, 0.f};
    f4 acc01 = acc00, acc10 = acc00, acc11 = acc00;
#pragma unroll
    for (int kc = 0; kc < 4; ++kc) {
        const float* p0 = Xg + col * 128 + kc * 32 + quad * 8;
        const float* p1 = p0 + 16 * 128;
        float r0[8], r1[8];
        *(float4*)(r0)     = *(const float4*)(p0);
        *(float4*)(r0 + 4) = *(const float4*)(p0 + 4);
        *(float4*)(r1)     = *(const float4*)(p1);
        *(float4*)(r1 + 4) = *(const float4*)(p1 + 4);
        short8 H0, L0, H1, L1;
        cvt_hilo(r0, H0, L0);
        cvt_hilo(r1, H1, L1);
        acc00 = mfma_bf16(H0, H0, acc00);
        acc00 = mfma_bf16(H0, L0, acc00);
        acc00 = mfma_bf16(L0, H0, acc00);
        acc01 = mfma_bf16(H0, H1, acc01);
        acc01 = mfma_bf16(H0, L1, acc01);
        acc01 = mfma_bf16(L0, H1, acc01);
        acc10 = mfma_bf16(H1, H0, acc10);
        acc10 = mfma_bf16(H1, L0, acc10);
        acc10 = mfma_bf16(L1, H0, acc10);
        acc11 = mfma_bf16(H1, H1, acc11);
        acc11 = mfma_bf16(H1, L1, acc11);
        acc11 = mfma_bf16(L1, H1, acc11);
    }

    float* Gw = sG[wid];
#pragma unroll
    for (int i = 0; i < 4; ++i) {   // C/D: col=lane&15, row=quad*4+i (G sym)
        int rw = quad * 4 + i;
        Gw[rw * 33 + col]             = acc00[i];
        Gw[rw * 33 + col + 16]        = acc01[i];
        Gw[(rw + 16) * 33 + col]      = acc10[i];
        Gw[(rw + 16) * 33 + col + 16] = acc11[i];
    }
    __syncthreads();

    // ---- Phase 2: normalized Gram row into VGPRs ----------------------------
    const int r = lane & 31;
    {
        float d = Gw[r * 33 + r];
        sInv[wid][r] = 1.0f / fmaxf(sqrtf(d), 1e-12f);
    }
    __syncthreads();

    float Grow[32];
    {
        float invr = sInv[wid][r];
#pragma unroll
        for (int j = 0; j < 32; ++j)
            Grow[j] = Gw[r * 33 + j] * (invr * sInv[wid][j]);
    }

    // ---- Phase 3: mu0 = normalize(mean(Xn)) in coefficient space ------------
    float a = 1.0f / 32.0f;
    float ga;
    {
        float s0 = 0, s1 = 0, s2 = 0, s3 = 0;
#pragma unroll
        for (int j = 0; j < 8; ++j) {
            s0 += Grow[j];
            s1 += Grow[j + 8];
            s2 += Grow[j + 16];
            s3 += Grow[j + 24];
        }
        ga = ((s0 + s1) + (s2 + s3)) * (1.0f / 32.0f);
        float n2   = rowsum32(a * ga);
        float inv0 = 1.0f / fmaxf(sqrtf(n2), 1e-12f);
        a  *= inv0;
        ga *= inv0;
    }

    // ---- Phase 4: Karcher iterations in 32-dim Gram space -------------------
    for (int it = 0; it < MAX_ITERS; ++it) {
        float x  = fminf(fmaxf(ga, -1.0f + CLIPV), 1.0f - CLIPV);
        float th = fast_acos(x);
        float st = fmaxf(sqrtf(fmaxf(1.0f - x * x, 0.0f)), EPSV);
        float w  = __fdividef(th, st);
        float C  = rowsum32(w * ga);               // sum_n w_n dot_n
        float beta = (w - C * a) * (1.0f / 32.0f); // v = sum beta_n Xn_n
        float gb0 = 0, gb1 = 0, gb2 = 0, gb3 = 0;  // (G beta)_r, 4 indep chains
#pragma unroll
        for (int j = 0; j < 8; ++j) {
            gb0 = fmaf(Grow[j],      rl(beta, j),      gb0);
            gb1 = fmaf(Grow[j + 8],  rl(beta, j + 8),  gb1);
            gb2 = fmaf(Grow[j + 16], rl(beta, j + 16), gb2);
            gb3 = fmaf(Grow[j + 24], rl(beta, j + 24), gb3);
        }
        float gb = (gb0 + gb1) + (gb2 + gb3);
        float vv = rowsum32(beta * gb);            // ||v||^2 = beta^T G beta
        float vs = fmaxf(sqrtf(fmaxf(vv, 0.0f)), EPSV);
        float cv = __cosf(vs);
        float sv = __fdividef(__sinf(vs), vs);
        a  = fmaf(sv, beta, cv * a);               // exp map (v perp mu)
        ga = fmaf(sv, gb, cv * ga);
        if (vs < 1e-6f) break;  // wave-uniform; residual drift < 2e-5 in mu
    }

    // ---- Phase 5: per-block partial loss (NO same-address atomics) ----------
    float xf = fminf(fmaxf(ga, -1.0f + CLIPV), 1.0f - CLIPV);
    float t  = fast_acos(xf);
    float ls = rowsum32(t * t);   // wave-uniform
    if (lane == 0) sPart[wid] = ls;
    __syncthreads();
    if (threadIdx.x == 0)
        ws[blockIdx.x] = (sPart[0] + sPart[1]) + (sPart[2] + sPart[3]);
}

__global__ void __launch_bounds__(256) reduce_partials(const float* __restrict__ ws,
                                                       float* __restrict__ out,
                                                       int n, float scale) {
    __shared__ float sred[4];
    float s = 0.f;
    for (int i = threadIdx.x; i < n; i += 256) s += ws[i];
#pragma unroll
    for (int m = 32; m >= 1; m >>= 1) s += __shfl_xor(s, m, 64);
    const int lane = threadIdx.x & 63, wid = threadIdx.x >> 6;
    if (lane == 0) sred[wid] = s;
    __syncthreads();
    if (threadIdx.x == 0)
        out[0] = ((sred[0] + sred[1]) + (sred[2] + sred[3])) * scale;
}

extern "C" void kernel_launch(void* const* d_in, const int* in_sizes, int n_in,
                              void* d_out, int out_size, void* d_ws, size_t ws_size,
                              hipStream_t stream) {
    const float* X = (const float*)d_in[0];
    float* out = (float*)d_out;
    float* ws = (float*)d_ws;
    int n_groups = in_sizes[0] / (32 * 128);   // 8000
    int blocks = (n_groups + 3) / 4;           // 2000 blocks, 1 group/wave
    karcher<<<blocks, 256, 0, stream>>>(X, ws, n_groups);
    reduce_partials<<<1, 256, 0, stream>>>(ws, out, blocks, 1.0f / (float)n_groups);
}